// Round 1
// baseline (262.709 us; speedup 1.0000x reference)
//
#include <hip/hip_runtime.h>
#include <math.h>

// One thread per token:
//  1) argmax over x[0,s,0:20]  (5x float4 loads, first-max semantics like jnp.argmax)
//  2) per-expert Linear(2,2) + softmax(2)
//  3) write y[s]; scatter into y2 via analytic inverse of the pu permutation:
//     rank = lower_bound(pu_index, s); dst = in_pu ? rank : P + s - rank
__global__ __launch_bounds__(256) void verblizer_fused_kernel(
    const float* __restrict__ x,     // [S,20]
    const float* __restrict__ h,     // [S,2]
    const float* __restrict__ W,     // [20,2,2]
    const float* __restrict__ b,     // [20,2]
    const int*   __restrict__ pu,    // [P] sorted unique
    float*       __restrict__ out,   // [2S*2]: y then y2
    int S, int P)
{
    __shared__ float sW[80];  // W[e][o][i] flat
    __shared__ float sb[40];
    int tid = threadIdx.x;
    if (tid < 80)  sW[tid] = W[tid];
    else if (tid < 120) sb[tid - 80] = b[tid - 80];
    __syncthreads();

    int s = blockIdx.x * blockDim.x + tid;
    if (s >= S) return;

    // ---- argmax over 20 contiguous floats (16B-aligned: 80B/token) ----
    const float4* xv = (const float4*)(x + (size_t)s * 20);
    float best = -INFINITY;
    int   bi   = 0;
#pragma unroll
    for (int j = 0; j < 5; ++j) {
        float4 v = xv[j];
        if (v.x > best) { best = v.x; bi = j * 4 + 0; }
        if (v.y > best) { best = v.y; bi = j * 4 + 1; }
        if (v.z > best) { best = v.z; bi = j * 4 + 2; }
        if (v.w > best) { best = v.w; bi = j * 4 + 3; }
    }

    // ---- Linear(2,2): y[o] = h0*W[e,o,0] + h1*W[e,o,1] + b[e,o] ----
    float2 hv = ((const float2*)h)[s];
    const float* we = sW + bi * 4;
    float y0 = fmaf(hv.x, we[0], fmaf(hv.y, we[1], sb[bi * 2 + 0]));
    float y1 = fmaf(hv.x, we[2], fmaf(hv.y, we[3], sb[bi * 2 + 1]));

    // ---- softmax over 2 ----
    float m  = fmaxf(y0, y1);
    float e0 = __expf(y0 - m);
    float e1 = __expf(y1 - m);
    float inv = 1.0f / (e0 + e1);
    float2 yo = make_float2(e0 * inv, e1 * inv);

    // output1: y[s]
    ((float2*)out)[s] = yo;

    // ---- inverse permutation scatter for output2 ----
    int lo = 0, hi = P;
    while (lo < hi) {               // lower_bound(pu, s)
        int mid = (lo + hi) >> 1;
        if (pu[mid] < s) lo = mid + 1; else hi = mid;
    }
    int dst = (lo < P && pu[lo] == s) ? lo : (P + s - lo);
    ((float2*)(out + (size_t)2 * S))[dst] = yo;
}

extern "C" void kernel_launch(void* const* d_in, const int* in_sizes, int n_in,
                              void* d_out, int out_size, void* d_ws, size_t ws_size,
                              hipStream_t stream) {
    const float* x  = (const float*)d_in[0];   // [1,S,20]
    const float* h  = (const float*)d_in[1];   // [S,2]
    const float* W  = (const float*)d_in[2];   // [20,2,2]
    const float* b  = (const float*)d_in[3];   // [20,2]
    const int*   pu = (const int*)d_in[4];     // [P]

    const int S = in_sizes[1] / 2;
    const int P = in_sizes[4];

    float* out = (float*)d_out;

    const int block = 256;
    const int grid  = (S + block - 1) / block;
    verblizer_fused_kernel<<<grid, block, 0, stream>>>(x, h, W, b, pu, out, S, P);
}